// Round 9
// baseline (114.887 us; speedup 1.0000x reference)
//
#include <hip/hip_runtime.h>

// Problem: B=2, C=6 (DTI lower-tri), H=W=D=64. fp32 in, fp32 out.
// out[b,c,x,y,z] = (R^T M R)[I[c],J[c]]
//   M = 3x3 symmetric from trilinear-warped DTI (border clamp, align_corners)
//   R = orthogonal polar factor of J = I + du/dx  (== U @ Vh of SVD(J))
// Pipeline: memset(bad=0) -> transpose_dti (channel-last, 8-float padded, in
// d_ws) -> warp_main (fp32, gathers hit 1-2 cache lines per corner-pair
// instead of ~12) -> rescue (fp64 re-solve of flagged voxels).
#define NVOX 262144          // 64^3
#define TOTAL (2 * NVOX)     // B * H * W * D
#define TBYTES ((size_t)TOTAL * 8 * 4)   // transposed dti: 16.8 MB

typedef float f2u __attribute__((ext_vector_type(2), aligned(4)));
typedef float f4u __attribute__((ext_vector_type(4), aligned(16)));

// dti (B,6,H,W,D) -> dst (B, voxel, 8) channel-last, 32 B/voxel, zero-padded.
__global__ __launch_bounds__(256)
void transpose_dti(const float* __restrict__ dti, float* __restrict__ dst)
{
    const int idx = blockIdx.x * 256 + threadIdx.x;   // TOTAL threads
    const int b = idx >> 18;
    const int r = idx & (NVOX - 1);
    const float* tb = dti + (size_t)b * 6 * NVOX;
    f4u lo, hi;
    lo.x = tb[r];            lo.y = tb[NVOX + r];
    lo.z = tb[2 * NVOX + r]; lo.w = tb[3 * NVOX + r];
    hi.x = tb[4 * NVOX + r]; hi.y = tb[5 * NVOX + r];
    hi.z = 0.0f;             hi.w = 0.0f;
    float* o = dst + (size_t)idx * 8;      // per-wave 2 KB contiguous
    *(f4u*)o = lo;
    *(f4u*)(o + 4) = hi;
}

// accumulate m[0..5] += q * lerp_z(corner-pair at pp), border-clamped top
__device__ __forceinline__ void acc_pair(const float* __restrict__ pp,
                                         bool ztop, float gz, float fz,
                                         float q, float m[6])
{
    const f4u a0 = *(const f4u*)pp;          // c0..c3 @ z0
    const f2u b0 = *(const f2u*)(pp + 4);    // c4,c5 @ z0
    const f4u a1 = *(const f4u*)(pp + 8);    // c0..c3 @ z1
    const f2u b1 = *(const f2u*)(pp + 12);   // c4,c5 @ z1
    const float z0c[6] = {a0.x, a0.y, a0.z, a0.w, b0.x, b0.y};
    const float z1c[6] = {a1.x, a1.y, a1.z, a1.w, b1.x, b1.y};
#pragma unroll
    for (int c = 0; c < 6; ++c) {
        const float v0 = ztop ? z1c[c] : z0c[c];
        m[c] += q * (v0 * gz + z1c[c] * fz);
    }
}

__global__ __launch_bounds__(256, 8)
void warp_main(const float* __restrict__ dti_t,   // channel-last (d_ws)
               const float* __restrict__ ddf,
               float* __restrict__ out,
               int* __restrict__ bad, int max_bad)
{
    const int idx = blockIdx.x * 256 + threadIdx.x;   // exactly TOTAL threads
    const int b = idx >> 18;
    const int r = idx & (NVOX - 1);
    const int x = r >> 12;
    const int y = (r >> 6) & 63;
    const int z = r & 63;              // == lane

    const float* db = ddf + (size_t)b * 3 * NVOX;

    // ---------------- displacement at center ----------------
    const float ux = db[r];
    const float uy = db[NVOX + r];
    const float uz = db[2 * NVOX + r];

    // ---------------- trilinear warp, border padding ----------------
    const float cx = fminf(fmaxf((float)x + ux, 0.0f), 63.0f);
    const float cy = fminf(fmaxf((float)y + uy, 0.0f), 63.0f);
    const float cz = fminf(fmaxf((float)z + uz, 0.0f), 63.0f);
    const float fx0 = floorf(cx), fy0 = floorf(cy), fz0 = floorf(cz);
    const float fx = cx - fx0, fy = cy - fy0, fz = cz - fz0;
    const int x0 = (int)fx0, y0 = (int)fy0, z0 = (int)fz0;
    const int x1 = min(x0 + 1, 63), y1 = min(y0 + 1, 63);

    const float gx = 1.0f - fx, gy = 1.0f - fy, gz = 1.0f - fz;
    const float q00 = gx * gy, q01 = gx * fy, q10 = fx * gy, q11 = fx * fy;

    // z0==63 only when cz==63 (fz=0): shift base to 62, take z1 slot for z0.
    const bool ztop = (z0 == 63);
    const int zb = ztop ? 62 : z0;
    const float* tt = dti_t + (size_t)b * NVOX * 8;
    const float* pp00 = tt + (size_t)((x0 * 64 + y0) * 64 + zb) * 8;
    const float* pp01 = tt + (size_t)((x0 * 64 + y1) * 64 + zb) * 8;
    const float* pp10 = tt + (size_t)((x1 * 64 + y0) * 64 + zb) * 8;
    const float* pp11 = tt + (size_t)((x1 * 64 + y1) * 64 + zb) * 8;

    float m[6] = {0, 0, 0, 0, 0, 0};
    acc_pair(pp00, ztop, gz, fz, q00, m);
    acc_pair(pp01, ztop, gz, fz, q01, m);
    acc_pair(pp10, ztop, gz, fz, q10, m);
    acc_pair(pp11, ztop, gz, fz, q11, m);

    // -------- Jacobian J = I + du/dx (np.gradient semantics), fp32 ---------
    const int xm = max(x - 1, 0), xp = min(x + 1, 63);
    const int ym = max(y - 1, 0), yp = min(y + 1, 63);
    const int zm = max(z - 1, 0), zp = min(z + 1, 63);
    const float sx = (xp - xm == 2) ? 0.5f : 1.0f;
    const float sy = (yp - ym == 2) ? 0.5f : 1.0f;
    const float sz = (zp - zm == 2) ? 0.5f : 1.0f;

    float P[3][3];
#pragma unroll
    for (int i = 0; i < 3; ++i) {
        const float* ui = db + i * NVOX;
        const float ctr = (i == 0) ? ux : (i == 1) ? uy : uz;
        P[i][0] = (ui[(xp * 64 + y) * 64 + z] - ui[(xm * 64 + y) * 64 + z]) * sx
                + (i == 0 ? 1.0f : 0.0f);
        P[i][1] = (ui[(x * 64 + yp) * 64 + z] - ui[(x * 64 + ym) * 64 + z]) * sy
                + (i == 1 ? 1.0f : 0.0f);
        // z-row lives in this wave: lane == z
        P[i][2] = (__shfl(ctr, zp) - __shfl(ctr, zm)) * sz + (i == 2 ? 1.0f : 0.0f);
    }

    // -------- fp32 scaled-Newton polar, 5 iters, division-free --------------
    bool ill = false;
#pragma unroll
    for (int it = 0; it < 5; ++it) {
        const float C00 = P[1][1] * P[2][2] - P[1][2] * P[2][1];
        const float C01 = P[1][2] * P[2][0] - P[1][0] * P[2][2];
        const float C02 = P[1][0] * P[2][1] - P[1][1] * P[2][0];
        const float C10 = P[0][2] * P[2][1] - P[0][1] * P[2][2];
        const float C11 = P[0][0] * P[2][2] - P[0][2] * P[2][0];
        const float C12 = P[0][1] * P[2][0] - P[0][0] * P[2][1];
        const float C20 = P[0][1] * P[1][2] - P[0][2] * P[1][1];
        const float C21 = P[0][2] * P[1][0] - P[0][0] * P[1][2];
        const float C22 = P[0][0] * P[1][1] - P[0][1] * P[1][0];
        const float det = P[0][0] * C00 + P[0][1] * C01 + P[0][2] * C02;

        const float n2 = P[0][0]*P[0][0] + P[0][1]*P[0][1] + P[0][2]*P[0][2]
                       + P[1][0]*P[1][0] + P[1][1]*P[1][1] + P[1][2]*P[1][2]
                       + P[2][0]*P[2][0] + P[2][1]*P[2][1] + P[2][2]*P[2][2];
        const float a2 = C00*C00 + C01*C01 + C02*C02
                       + C10*C10 + C11*C11 + C12*C12
                       + C20*C20 + C21*C21 + C22*C22;

        const float ad = fmaxf(fabsf(det), 1e-30f);
        if (it == 0) ill = (n2 * a2 > 1e8f * ad * ad);   // cond_F > 1e4

        const float t   = fmaxf(sqrtf(a2) * rsqrtf(n2), 1e-20f);
        const float it2 = rsqrtf(t * ad);
        const float sg  = (det < 0.0f) ? -0.5f : 0.5f;
        const float c1  = 0.5f * t * it2;
        const float c2  = sg * it2;

        P[0][0] = c1 * P[0][0] + c2 * C00;  P[0][1] = c1 * P[0][1] + c2 * C01;  P[0][2] = c1 * P[0][2] + c2 * C02;
        P[1][0] = c1 * P[1][0] + c2 * C10;  P[1][1] = c1 * P[1][1] + c2 * C11;  P[1][2] = c1 * P[1][2] + c2 * C12;
        P[2][0] = c1 * P[2][0] + c2 * C20;  P[2][1] = c1 * P[2][1] + c2 * C21;  P[2][2] = c1 * P[2][2] + c2 * C22;
    }

    // ---------------- A = R^T * M * R (lower-tri only) ----------------
    const float M3[3][3] = {{m[0], m[1], m[3]},
                            {m[1], m[2], m[4]},
                            {m[3], m[4], m[5]}};
    float T[3][3];
#pragma unroll
    for (int i = 0; i < 3; ++i)
#pragma unroll
        for (int j = 0; j < 3; ++j)
            T[i][j] = P[0][i] * M3[0][j] + P[1][i] * M3[1][j] + P[2][i] * M3[2][j];

    float* ob = out + (size_t)b * 6 * NVOX;
    ob[0 * NVOX + r] = T[0][0]*P[0][0] + T[0][1]*P[1][0] + T[0][2]*P[2][0];
    ob[1 * NVOX + r] = T[1][0]*P[0][0] + T[1][1]*P[1][0] + T[1][2]*P[2][0];
    ob[2 * NVOX + r] = T[1][0]*P[0][1] + T[1][1]*P[1][1] + T[1][2]*P[2][1];
    ob[3 * NVOX + r] = T[2][0]*P[0][0] + T[2][1]*P[1][0] + T[2][2]*P[2][0];
    ob[4 * NVOX + r] = T[2][0]*P[0][1] + T[2][1]*P[1][1] + T[2][2]*P[2][1];
    ob[5 * NVOX + r] = T[2][0]*P[0][2] + T[2][1]*P[1][2] + T[2][2]*P[2][2];

    // ---------------- flag ill-conditioned voxels for fp64 rescue -----------
    if (ill) {
        const int slot = atomicAdd(bad, 1);
        if (slot < max_bad) bad[1 + slot] = idx;
    }
}

// fp64 re-solve for the ~1e-4 fraction of voxels with near-singular J.
__global__ __launch_bounds__(256)
void rescue(const float* __restrict__ dti,
            const float* __restrict__ ddf,
            float* __restrict__ out,
            const int* __restrict__ bad, int max_bad)
{
    const int n = min(bad[0], max_bad);
    for (int k = blockIdx.x * 256 + threadIdx.x; k < n; k += 4 * 256) {
        const int idx = bad[1 + k];
        const int b = idx >> 18;
        const int r = idx & (NVOX - 1);
        const int x = r >> 12;
        const int y = (r >> 6) & 63;
        const int z = r & 63;

        const float* db = ddf + (size_t)b * 3 * NVOX;

        // warp (fp32 — M is well-conditioned)
        const float cx = fminf(fmaxf((float)x + db[r], 0.0f), 63.0f);
        const float cy = fminf(fmaxf((float)y + db[NVOX + r], 0.0f), 63.0f);
        const float cz = fminf(fmaxf((float)z + db[2 * NVOX + r], 0.0f), 63.0f);
        const float fx0 = floorf(cx), fy0 = floorf(cy), fz0 = floorf(cz);
        const float fx = cx - fx0, fy = cy - fy0, fz = cz - fz0;
        const int x0 = (int)fx0, y0 = (int)fy0, z0 = (int)fz0;
        const int x1 = min(x0 + 1, 63), y1 = min(y0 + 1, 63), z1 = min(z0 + 1, 63);
        const float gx = 1.0f - fx, gy = 1.0f - fy, gz = 1.0f - fz;
        const float w000 = gx*gy*gz, w001 = gx*gy*fz, w010 = gx*fy*gz, w011 = gx*fy*fz;
        const float w100 = fx*gy*gz, w101 = fx*gy*fz, w110 = fx*fy*gz, w111 = fx*fy*fz;
        const int o000 = (x0*64+y0)*64+z0, o001 = (x0*64+y0)*64+z1;
        const int o010 = (x0*64+y1)*64+z0, o011 = (x0*64+y1)*64+z1;
        const int o100 = (x1*64+y0)*64+z0, o101 = (x1*64+y0)*64+z1;
        const int o110 = (x1*64+y1)*64+z0, o111 = (x1*64+y1)*64+z1;

        const float* tb = dti + (size_t)b * 6 * NVOX;
        float m[6];
        for (int c = 0; c < 6; ++c) {
            const float* tc = tb + c * NVOX;
            m[c] = w000*tc[o000] + w001*tc[o001] + w010*tc[o010] + w011*tc[o011]
                 + w100*tc[o100] + w101*tc[o101] + w110*tc[o110] + w111*tc[o111];
        }

        // Jacobian fp64
        const int xm = max(x-1,0), xp = min(x+1,63);
        const int ym = max(y-1,0), yp = min(y+1,63);
        const int zm = max(z-1,0), zp = min(z+1,63);
        const double sx = (xp-xm==2)?0.5:1.0, sy = (yp-ym==2)?0.5:1.0, sz = (zp-zm==2)?0.5:1.0;
        double X[3][3];
        for (int i = 0; i < 3; ++i) {
            const float* ui = db + i * NVOX;
            X[i][0] = ((double)ui[(xp*64+y)*64+z] - (double)ui[(xm*64+y)*64+z]) * sx + (i==0?1.0:0.0);
            X[i][1] = ((double)ui[(x*64+yp)*64+z] - (double)ui[(x*64+ym)*64+z]) * sy + (i==1?1.0:0.0);
            X[i][2] = ((double)ui[(x*64+y)*64+zp] - (double)ui[(x*64+y)*64+zm]) * sz + (i==2?1.0:0.0);
        }

        // 14-iter normalized scaled-Newton polar (overflow-proof)
        for (int it = 0; it < 14; ++it) {
            double mx = 0.0;
            for (int i = 0; i < 3; ++i)
                for (int j = 0; j < 3; ++j) mx = fmax(mx, fabs(X[i][j]));
            const double s = 1.0 / fmax(mx, 1e-300);
            for (int i = 0; i < 3; ++i)
                for (int j = 0; j < 3; ++j) X[i][j] *= s;

            const double C00 = X[1][1]*X[2][2] - X[1][2]*X[2][1];
            const double C01 = X[1][2]*X[2][0] - X[1][0]*X[2][2];
            const double C02 = X[1][0]*X[2][1] - X[1][1]*X[2][0];
            const double C10 = X[0][2]*X[2][1] - X[0][1]*X[2][2];
            const double C11 = X[0][0]*X[2][2] - X[0][2]*X[2][0];
            const double C12 = X[0][1]*X[2][0] - X[0][0]*X[2][1];
            const double C20 = X[0][1]*X[1][2] - X[0][2]*X[1][1];
            const double C21 = X[0][2]*X[1][0] - X[0][0]*X[1][2];
            const double C22 = X[0][0]*X[1][1] - X[0][1]*X[1][0];
            const double det = X[0][0]*C00 + X[0][1]*C01 + X[0][2]*C02;
            const double n2 = X[0][0]*X[0][0]+X[0][1]*X[0][1]+X[0][2]*X[0][2]
                            + X[1][0]*X[1][0]+X[1][1]*X[1][1]+X[1][2]*X[1][2]
                            + X[2][0]*X[2][0]+X[2][1]*X[2][1]+X[2][2]*X[2][2];
            const double a2 = C00*C00+C01*C01+C02*C02 + C10*C10+C11*C11+C12*C12
                            + C20*C20+C21*C21+C22*C22;
            const double t2 = fmax(sqrt(a2 / n2), 1e-150);
            const double ad = fmax(fabs(det), 1e-280);
            const double sg = (det < 0.0) ? -1.0 : 1.0;
            const double c1 = 0.5 * sqrt(t2 / ad);
            const double c2 = 0.5 * sg / sqrt(t2 * ad);
            X[0][0]=c1*X[0][0]+c2*C00; X[0][1]=c1*X[0][1]+c2*C01; X[0][2]=c1*X[0][2]+c2*C02;
            X[1][0]=c1*X[1][0]+c2*C10; X[1][1]=c1*X[1][1]+c2*C11; X[1][2]=c1*X[1][2]+c2*C12;
            X[2][0]=c1*X[2][0]+c2*C20; X[2][1]=c1*X[2][1]+c2*C21; X[2][2]=c1*X[2][2]+c2*C22;
        }

        const double M3[3][3] = {{(double)m[0], (double)m[1], (double)m[3]},
                                 {(double)m[1], (double)m[2], (double)m[4]},
                                 {(double)m[3], (double)m[4], (double)m[5]}};
        double T[3][3], A[3][3];
        for (int i = 0; i < 3; ++i)
            for (int j = 0; j < 3; ++j)
                T[i][j] = X[0][i]*M3[0][j] + X[1][i]*M3[1][j] + X[2][i]*M3[2][j];
        for (int i = 0; i < 3; ++i)
            for (int j = 0; j < 3; ++j)
                A[i][j] = T[i][0]*X[0][j] + T[i][1]*X[1][j] + T[i][2]*X[2][j];

        float* ob = out + (size_t)b * 6 * NVOX;
        ob[0 * NVOX + r] = (float)A[0][0];
        ob[1 * NVOX + r] = (float)A[1][0];
        ob[2 * NVOX + r] = (float)A[1][1];
        ob[3 * NVOX + r] = (float)A[2][0];
        ob[4 * NVOX + r] = (float)A[2][1];
        ob[5 * NVOX + r] = (float)A[2][2];
    }
}

extern "C" void kernel_launch(void* const* d_in, const int* in_sizes, int n_in,
                              void* d_out, int out_size, void* d_ws, size_t ws_size,
                              hipStream_t stream) {
    const float* dti = (const float*)d_in[0];
    const float* ddf = (const float*)d_in[1];
    float* out = (float*)d_out;
    float* dti_t = (float*)d_ws;                       // 16.8 MB, 32B-aligned
    int* bad = (int*)((char*)d_ws + TBYTES);           // counter + index list
    const int max_bad = 8192;

    hipMemsetAsync(bad, 0, sizeof(int), stream);       // graph-capture-legal
    transpose_dti<<<TOTAL / 256, 256, 0, stream>>>(dti, dti_t);
    warp_main<<<TOTAL / 256, 256, 0, stream>>>(dti_t, ddf, out, bad, max_bad);
    rescue<<<4, 256, 0, stream>>>(dti, ddf, out, bad, max_bad);
}

// Round 10
// 112.568 us; speedup vs baseline: 1.0206x; 1.0206x over previous
//
#include <hip/hip_runtime.h>

// Problem: B=2, C=6 (DTI lower-tri), H=W=D=64. fp32 in, fp32 out.
// out[b,c,x,y,z] = (R^T M R)[I[c],J[c]]
//   M = 3x3 symmetric from trilinear-warped DTI (border clamp, align_corners)
//   R = orthogonal polar factor of J = I + du/dx  (== U @ Vh of SVD(J))
// Pipeline: memset(bad=0) -> transpose_dti (channel-last 8-float voxels in
// d_ws) -> warp_main (gathers = 1-2 fully-consumed cache lines / corner-pair)
// -> rescue (fp64 re-solve of flagged voxels).
// R10: XCD-aware swizzle (v = (blk%8)*256 + blk/8) on BOTH transpose and
// warp_main so each XCD's 4MB L2 owns its 16-x-plane slab: transpose writes
// and gather reads stay XCD-local (R9 lacked this -> dti_t came from HBM).
#define NVOX 262144          // 64^3
#define TOTAL (2 * NVOX)     // B * H * W * D
#define NBLK (TOTAL / 256)   // 2048 blocks
#define TBYTES ((size_t)TOTAL * 8 * 4)   // transposed dti: 16.8 MB

typedef float f2u __attribute__((ext_vector_type(2), aligned(4)));
typedef float f4u __attribute__((ext_vector_type(4), aligned(16)));

__device__ __forceinline__ int swizzle_block() {
    // XCD k (= blockIdx%8 under round-robin dispatch) gets contiguous virtual
    // blocks [k*256, (k+1)*256) = 16 consecutive x-planes -> 4MB-L2-resident.
    return (blockIdx.x & 7) * (NBLK / 8) + (blockIdx.x >> 3);
}

// dti (B,6,H,W,D) -> dst (B, voxel, 8) channel-last, 32 B/voxel, zero-padded.
__global__ __launch_bounds__(256, 8)
void transpose_dti(const float* __restrict__ dti, float* __restrict__ dst)
{
    const int idx = swizzle_block() * 256 + threadIdx.x;   // TOTAL threads
    const int b = idx >> 18;
    const int r = idx & (NVOX - 1);
    const float* tb = dti + (size_t)b * 6 * NVOX;
    f4u lo, hi;
    lo.x = tb[r];            lo.y = tb[NVOX + r];
    lo.z = tb[2 * NVOX + r]; lo.w = tb[3 * NVOX + r];
    hi.x = tb[4 * NVOX + r]; hi.y = tb[5 * NVOX + r];
    hi.z = 0.0f;             hi.w = 0.0f;
    float* o = dst + (size_t)idx * 8;      // per-wave 2 KB contiguous
    *(f4u*)o = lo;
    *(f4u*)(o + 4) = hi;
}

// accumulate m[0..5] += q * lerp_z(corner-pair at pp), border-clamped top
__device__ __forceinline__ void acc_pair(const float* __restrict__ pp,
                                         bool ztop, float gz, float fz,
                                         float q, float m[6])
{
    const f4u a0 = *(const f4u*)pp;          // c0..c3 @ z0
    const f2u b0 = *(const f2u*)(pp + 4);    // c4,c5 @ z0
    const f4u a1 = *(const f4u*)(pp + 8);    // c0..c3 @ z1
    const f2u b1 = *(const f2u*)(pp + 12);   // c4,c5 @ z1
    const float z0c[6] = {a0.x, a0.y, a0.z, a0.w, b0.x, b0.y};
    const float z1c[6] = {a1.x, a1.y, a1.z, a1.w, b1.x, b1.y};
#pragma unroll
    for (int c = 0; c < 6; ++c) {
        const float v0 = ztop ? z1c[c] : z0c[c];
        m[c] += q * (v0 * gz + z1c[c] * fz);
    }
}

__global__ __launch_bounds__(256, 8)
void warp_main(const float* __restrict__ dti_t,   // channel-last (d_ws)
               const float* __restrict__ ddf,
               float* __restrict__ out,
               int* __restrict__ bad, int max_bad)
{
    const int idx = swizzle_block() * 256 + threadIdx.x;   // same region as
    const int b = idx >> 18;                               // transpose: L2-local
    const int r = idx & (NVOX - 1);
    const int x = r >> 12;
    const int y = (r >> 6) & 63;
    const int z = r & 63;              // == lane

    const float* db = ddf + (size_t)b * 3 * NVOX;

    // ---- center displacements ----
    const float ux = db[r];
    const float uy = db[NVOX + r];
    const float uz = db[2 * NVOX + r];

    // ---- Jacobian neighbor loads FIRST (independent of warp-coord chain) ---
    const int xm = max(x - 1, 0), xp = min(x + 1, 63);
    const int ym = max(y - 1, 0), yp = min(y + 1, 63);
    const int zm = max(z - 1, 0), zp = min(z + 1, 63);
    const float sx = (xp - xm == 2) ? 0.5f : 1.0f;
    const float sy = (yp - ym == 2) ? 0.5f : 1.0f;
    const float sz = (zp - zm == 2) ? 0.5f : 1.0f;

    float jx[3][2], jy[3][2];
#pragma unroll
    for (int i = 0; i < 3; ++i) {
        const float* ui = db + i * NVOX;
        jx[i][0] = ui[(xm * 64 + y) * 64 + z];
        jx[i][1] = ui[(xp * 64 + y) * 64 + z];
        jy[i][0] = ui[(x * 64 + ym) * 64 + z];
        jy[i][1] = ui[(x * 64 + yp) * 64 + z];
    }

    // ---------------- trilinear warp, border padding ----------------
    const float cx = fminf(fmaxf((float)x + ux, 0.0f), 63.0f);
    const float cy = fminf(fmaxf((float)y + uy, 0.0f), 63.0f);
    const float cz = fminf(fmaxf((float)z + uz, 0.0f), 63.0f);
    const float fx0 = floorf(cx), fy0 = floorf(cy), fz0 = floorf(cz);
    const float fx = cx - fx0, fy = cy - fy0, fz = cz - fz0;
    const int x0 = (int)fx0, y0 = (int)fy0, z0 = (int)fz0;
    const int x1 = min(x0 + 1, 63), y1 = min(y0 + 1, 63);

    const float gx = 1.0f - fx, gy = 1.0f - fy, gz = 1.0f - fz;
    const float q00 = gx * gy, q01 = gx * fy, q10 = fx * gy, q11 = fx * fy;

    // z0==63 only when cz==63 (fz=0): shift base to 62, take z1 slot for z0.
    const bool ztop = (z0 == 63);
    const int zb = ztop ? 62 : z0;
    const float* tt = dti_t + (size_t)b * NVOX * 8;
    const float* pp00 = tt + (size_t)((x0 * 64 + y0) * 64 + zb) * 8;
    const float* pp01 = tt + (size_t)((x0 * 64 + y1) * 64 + zb) * 8;
    const float* pp10 = tt + (size_t)((x1 * 64 + y0) * 64 + zb) * 8;
    const float* pp11 = tt + (size_t)((x1 * 64 + y1) * 64 + zb) * 8;

    float m[6] = {0, 0, 0, 0, 0, 0};
    acc_pair(pp00, ztop, gz, fz, q00, m);
    acc_pair(pp01, ztop, gz, fz, q01, m);
    acc_pair(pp10, ztop, gz, fz, q10, m);
    acc_pair(pp11, ztop, gz, fz, q11, m);

    // -------- Jacobian J = I + du/dx (np.gradient semantics), fp32 ---------
    float P[3][3];
#pragma unroll
    for (int i = 0; i < 3; ++i) {
        const float ctr = (i == 0) ? ux : (i == 1) ? uy : uz;
        P[i][0] = (jx[i][1] - jx[i][0]) * sx + (i == 0 ? 1.0f : 0.0f);
        P[i][1] = (jy[i][1] - jy[i][0]) * sy + (i == 1 ? 1.0f : 0.0f);
        // z-row lives in this wave: lane == z
        P[i][2] = (__shfl(ctr, zp) - __shfl(ctr, zm)) * sz + (i == 2 ? 1.0f : 0.0f);
    }

    // -------- fp32 scaled-Newton polar, 5 iters, division-free --------------
    bool ill = false;
#pragma unroll
    for (int it = 0; it < 5; ++it) {
        const float C00 = P[1][1] * P[2][2] - P[1][2] * P[2][1];
        const float C01 = P[1][2] * P[2][0] - P[1][0] * P[2][2];
        const float C02 = P[1][0] * P[2][1] - P[1][1] * P[2][0];
        const float C10 = P[0][2] * P[2][1] - P[0][1] * P[2][2];
        const float C11 = P[0][0] * P[2][2] - P[0][2] * P[2][0];
        const float C12 = P[0][1] * P[2][0] - P[0][0] * P[2][1];
        const float C20 = P[0][1] * P[1][2] - P[0][2] * P[1][1];
        const float C21 = P[0][2] * P[1][0] - P[0][0] * P[1][2];
        const float C22 = P[0][0] * P[1][1] - P[0][1] * P[1][0];
        const float det = P[0][0] * C00 + P[0][1] * C01 + P[0][2] * C02;

        const float n2 = P[0][0]*P[0][0] + P[0][1]*P[0][1] + P[0][2]*P[0][2]
                       + P[1][0]*P[1][0] + P[1][1]*P[1][1] + P[1][2]*P[1][2]
                       + P[2][0]*P[2][0] + P[2][1]*P[2][1] + P[2][2]*P[2][2];
        const float a2 = C00*C00 + C01*C01 + C02*C02
                       + C10*C10 + C11*C11 + C12*C12
                       + C20*C20 + C21*C21 + C22*C22;

        const float ad = fmaxf(fabsf(det), 1e-30f);
        if (it == 0) ill = (n2 * a2 > 1e8f * ad * ad);   // cond_F > 1e4

        const float t   = fmaxf(sqrtf(a2) * rsqrtf(n2), 1e-20f);
        const float it2 = rsqrtf(t * ad);
        const float sg  = (det < 0.0f) ? -0.5f : 0.5f;
        const float c1  = 0.5f * t * it2;
        const float c2  = sg * it2;

        P[0][0] = c1 * P[0][0] + c2 * C00;  P[0][1] = c1 * P[0][1] + c2 * C01;  P[0][2] = c1 * P[0][2] + c2 * C02;
        P[1][0] = c1 * P[1][0] + c2 * C10;  P[1][1] = c1 * P[1][1] + c2 * C11;  P[1][2] = c1 * P[1][2] + c2 * C12;
        P[2][0] = c1 * P[2][0] + c2 * C20;  P[2][1] = c1 * P[2][1] + c2 * C21;  P[2][2] = c1 * P[2][2] + c2 * C22;
    }

    // ---------------- A = R^T * M * R (lower-tri only) ----------------
    const float M3[3][3] = {{m[0], m[1], m[3]},
                            {m[1], m[2], m[4]},
                            {m[3], m[4], m[5]}};
    float T[3][3];
#pragma unroll
    for (int i = 0; i < 3; ++i)
#pragma unroll
        for (int j = 0; j < 3; ++j)
            T[i][j] = P[0][i] * M3[0][j] + P[1][i] * M3[1][j] + P[2][i] * M3[2][j];

    float* ob = out + (size_t)b * 6 * NVOX;
    ob[0 * NVOX + r] = T[0][0]*P[0][0] + T[0][1]*P[1][0] + T[0][2]*P[2][0];
    ob[1 * NVOX + r] = T[1][0]*P[0][0] + T[1][1]*P[1][0] + T[1][2]*P[2][0];
    ob[2 * NVOX + r] = T[1][0]*P[0][1] + T[1][1]*P[1][1] + T[1][2]*P[2][1];
    ob[3 * NVOX + r] = T[2][0]*P[0][0] + T[2][1]*P[1][0] + T[2][2]*P[2][0];
    ob[4 * NVOX + r] = T[2][0]*P[0][1] + T[2][1]*P[1][1] + T[2][2]*P[2][1];
    ob[5 * NVOX + r] = T[2][0]*P[0][2] + T[2][1]*P[1][2] + T[2][2]*P[2][2];

    // ---------------- flag ill-conditioned voxels for fp64 rescue -----------
    if (ill) {
        const int slot = atomicAdd(bad, 1);
        if (slot < max_bad) bad[1 + slot] = idx;
    }
}

// fp64 re-solve for the ~1e-4 fraction of voxels with near-singular J.
__global__ __launch_bounds__(256)
void rescue(const float* __restrict__ dti,
            const float* __restrict__ ddf,
            float* __restrict__ out,
            const int* __restrict__ bad, int max_bad)
{
    const int n = min(bad[0], max_bad);
    for (int k = blockIdx.x * 256 + threadIdx.x; k < n; k += 4 * 256) {
        const int idx = bad[1 + k];
        const int b = idx >> 18;
        const int r = idx & (NVOX - 1);
        const int x = r >> 12;
        const int y = (r >> 6) & 63;
        const int z = r & 63;

        const float* db = ddf + (size_t)b * 3 * NVOX;

        // warp (fp32 — M is well-conditioned)
        const float cx = fminf(fmaxf((float)x + db[r], 0.0f), 63.0f);
        const float cy = fminf(fmaxf((float)y + db[NVOX + r], 0.0f), 63.0f);
        const float cz = fminf(fmaxf((float)z + db[2 * NVOX + r], 0.0f), 63.0f);
        const float fx0 = floorf(cx), fy0 = floorf(cy), fz0 = floorf(cz);
        const float fx = cx - fx0, fy = cy - fy0, fz = cz - fz0;
        const int x0 = (int)fx0, y0 = (int)fy0, z0 = (int)fz0;
        const int x1 = min(x0 + 1, 63), y1 = min(y0 + 1, 63), z1 = min(z0 + 1, 63);
        const float gx = 1.0f - fx, gy = 1.0f - fy, gz = 1.0f - fz;
        const float w000 = gx*gy*gz, w001 = gx*gy*fz, w010 = gx*fy*gz, w011 = gx*fy*fz;
        const float w100 = fx*gy*gz, w101 = fx*gy*fz, w110 = fx*fy*gz, w111 = fx*fy*fz;
        const int o000 = (x0*64+y0)*64+z0, o001 = (x0*64+y0)*64+z1;
        const int o010 = (x0*64+y1)*64+z0, o011 = (x0*64+y1)*64+z1;
        const int o100 = (x1*64+y0)*64+z0, o101 = (x1*64+y0)*64+z1;
        const int o110 = (x1*64+y1)*64+z0, o111 = (x1*64+y1)*64+z1;

        const float* tb = dti + (size_t)b * 6 * NVOX;
        float m[6];
        for (int c = 0; c < 6; ++c) {
            const float* tc = tb + c * NVOX;
            m[c] = w000*tc[o000] + w001*tc[o001] + w010*tc[o010] + w011*tc[o011]
                 + w100*tc[o100] + w101*tc[o101] + w110*tc[o110] + w111*tc[o111];
        }

        // Jacobian fp64
        const int xm = max(x-1,0), xp = min(x+1,63);
        const int ym = max(y-1,0), yp = min(y+1,63);
        const int zm = max(z-1,0), zp = min(z+1,63);
        const double sx = (xp-xm==2)?0.5:1.0, sy = (yp-ym==2)?0.5:1.0, sz = (zp-zm==2)?0.5:1.0;
        double X[3][3];
        for (int i = 0; i < 3; ++i) {
            const float* ui = db + i * NVOX;
            X[i][0] = ((double)ui[(xp*64+y)*64+z] - (double)ui[(xm*64+y)*64+z]) * sx + (i==0?1.0:0.0);
            X[i][1] = ((double)ui[(x*64+yp)*64+z] - (double)ui[(x*64+ym)*64+z]) * sy + (i==1?1.0:0.0);
            X[i][2] = ((double)ui[(x*64+y)*64+zp] - (double)ui[(x*64+y)*64+zm]) * sz + (i==2?1.0:0.0);
        }

        // 14-iter normalized scaled-Newton polar (overflow-proof)
        for (int it = 0; it < 14; ++it) {
            double mx = 0.0;
            for (int i = 0; i < 3; ++i)
                for (int j = 0; j < 3; ++j) mx = fmax(mx, fabs(X[i][j]));
            const double s = 1.0 / fmax(mx, 1e-300);
            for (int i = 0; i < 3; ++i)
                for (int j = 0; j < 3; ++j) X[i][j] *= s;

            const double C00 = X[1][1]*X[2][2] - X[1][2]*X[2][1];
            const double C01 = X[1][2]*X[2][0] - X[1][0]*X[2][2];
            const double C02 = X[1][0]*X[2][1] - X[1][1]*X[2][0];
            const double C10 = X[0][2]*X[2][1] - X[0][1]*X[2][2];
            const double C11 = X[0][0]*X[2][2] - X[0][2]*X[2][0];
            const double C12 = X[0][1]*X[2][0] - X[0][0]*X[2][1];
            const double C20 = X[0][1]*X[1][2] - X[0][2]*X[1][1];
            const double C21 = X[0][2]*X[1][0] - X[0][0]*X[1][2];
            const double C22 = X[0][0]*X[1][1] - X[0][1]*X[1][0];
            const double det = X[0][0]*C00 + X[0][1]*C01 + X[0][2]*C02;
            const double n2 = X[0][0]*X[0][0]+X[0][1]*X[0][1]+X[0][2]*X[0][2]
                            + X[1][0]*X[1][0]+X[1][1]*X[1][1]+X[1][2]*X[1][2]
                            + X[2][0]*X[2][0]+X[2][1]*X[2][1]+X[2][2]*X[2][2];
            const double a2 = C00*C00+C01*C01+C02*C02 + C10*C10+C11*C11+C12*C12
                            + C20*C20+C21*C21+C22*C22;
            const double t2 = fmax(sqrt(a2 / n2), 1e-150);
            const double ad = fmax(fabs(det), 1e-280);
            const double sg = (det < 0.0) ? -1.0 : 1.0;
            const double c1 = 0.5 * sqrt(t2 / ad);
            const double c2 = 0.5 * sg / sqrt(t2 * ad);
            X[0][0]=c1*X[0][0]+c2*C00; X[0][1]=c1*X[0][1]+c2*C01; X[0][2]=c1*X[0][2]+c2*C02;
            X[1][0]=c1*X[1][0]+c2*C10; X[1][1]=c1*X[1][1]+c2*C11; X[1][2]=c1*X[1][2]+c2*C12;
            X[2][0]=c1*X[2][0]+c2*C20; X[2][1]=c1*X[2][1]+c2*C21; X[2][2]=c1*X[2][2]+c2*C22;
        }

        const double M3[3][3] = {{(double)m[0], (double)m[1], (double)m[3]},
                                 {(double)m[1], (double)m[2], (double)m[4]},
                                 {(double)m[3], (double)m[4], (double)m[5]}};
        double T[3][3], A[3][3];
        for (int i = 0; i < 3; ++i)
            for (int j = 0; j < 3; ++j)
                T[i][j] = X[0][i]*M3[0][j] + X[1][i]*M3[1][j] + X[2][i]*M3[2][j];
        for (int i = 0; i < 3; ++i)
            for (int j = 0; j < 3; ++j)
                A[i][j] = T[i][0]*X[0][j] + T[i][1]*X[1][j] + T[i][2]*X[2][j];

        float* ob = out + (size_t)b * 6 * NVOX;
        ob[0 * NVOX + r] = (float)A[0][0];
        ob[1 * NVOX + r] = (float)A[1][0];
        ob[2 * NVOX + r] = (float)A[1][1];
        ob[3 * NVOX + r] = (float)A[2][0];
        ob[4 * NVOX + r] = (float)A[2][1];
        ob[5 * NVOX + r] = (float)A[2][2];
    }
}

extern "C" void kernel_launch(void* const* d_in, const int* in_sizes, int n_in,
                              void* d_out, int out_size, void* d_ws, size_t ws_size,
                              hipStream_t stream) {
    const float* dti = (const float*)d_in[0];
    const float* ddf = (const float*)d_in[1];
    float* out = (float*)d_out;
    float* dti_t = (float*)d_ws;                       // 16.8 MB, 32B-aligned
    int* bad = (int*)((char*)d_ws + TBYTES);           // counter + index list
    const int max_bad = 8192;

    hipMemsetAsync(bad, 0, sizeof(int), stream);       // graph-capture-legal
    transpose_dti<<<NBLK, 256, 0, stream>>>(dti, dti_t);
    warp_main<<<NBLK, 256, 0, stream>>>(dti_t, ddf, out, bad, max_bad);
    rescue<<<4, 256, 0, stream>>>(dti, ddf, out, bad, max_bad);
}